// Round 3
// baseline (139.313 us; speedup 1.0000x reference)
//
#include <hip/hip_runtime.h>
#include <math.h>

#define D 256          // feature dim (fixed by reference)
#define NREL 16        // relation count

// ---------------------------------------------------------------------------
// Kernel A: y[n][r] = dot(x[n], W[r]) for r in [0,16), xr[n] = dot(x[n], root)
// Block = 256 threads, handles 64 nodes. thread t: node = t&63, rgroup = t>>6.
// Each thread accumulates 4 relation dots (+ root for rgroup==3) over the full
// row, reading x from LDS (stride-65 pad -> conflict-free) and W via
// wave-uniform addresses (scalar loads).
// ---------------------------------------------------------------------------
__global__ __launch_bounds__(256) void rgcn_y_kernel(
    const float* __restrict__ x, const float* __restrict__ w,
    const float* __restrict__ root, float* __restrict__ y,
    float* __restrict__ xr, int n)
{
    __shared__ float lds[64 * 65];
    const int t = threadIdx.x;
    const int nl = t & 63;
    const int rg = __builtin_amdgcn_readfirstlane(t >> 6);  // wave-uniform
    const int node = blockIdx.x * 64 + nl;
    const int base = blockIdx.x * 64;

    const float* w0 = w + (size_t)(rg * 4 + 0) * D;
    const float* w1 = w + (size_t)(rg * 4 + 1) * D;
    const float* w2 = w + (size_t)(rg * 4 + 2) * D;
    const float* w3 = w + (size_t)(rg * 4 + 3) * D;
    const float* w4 = (rg == 3) ? root : w0;  // root handled by rgroup 3

    float acc0 = 0.f, acc1 = 0.f, acc2 = 0.f, acc3 = 0.f, accR = 0.f;

    for (int c = 0; c < 4; ++c) {  // 4 chunks of 64 features
        // ---- stage x[base..base+64)[c*64 .. c*64+64) into LDS ----
        #pragma unroll
        for (int j = 0; j < 4; ++j) {
            int flat = j * 256 + t;      // 0..1023
            int snl  = flat >> 4;        // staged node local 0..63
            int f4   = flat & 15;        // float4 index within 64-float chunk
            int gn   = base + snl;
            float4 v = make_float4(0.f, 0.f, 0.f, 0.f);
            if (gn < n)
                v = *reinterpret_cast<const float4*>(
                        x + (size_t)gn * D + c * 64 + f4 * 4);
            int a = snl * 65 + f4 * 4;
            lds[a + 0] = v.x; lds[a + 1] = v.y;
            lds[a + 2] = v.z; lds[a + 3] = v.w;
        }
        __syncthreads();

        const float* wc0 = w0 + c * 64;
        const float* wc1 = w1 + c * 64;
        const float* wc2 = w2 + c * 64;
        const float* wc3 = w3 + c * 64;
        const float* wc4 = w4 + c * 64;
        #pragma unroll
        for (int d = 0; d < 64; ++d) {
            float xv = lds[nl * 65 + d];
            acc0 = fmaf(xv, wc0[d], acc0);
            acc1 = fmaf(xv, wc1[d], acc1);
            acc2 = fmaf(xv, wc2[d], acc2);
            acc3 = fmaf(xv, wc3[d], acc3);
            accR = fmaf(xv, wc4[d], accR);
        }
        __syncthreads();
    }

    if (node < n) {
        float4 o; o.x = acc0; o.y = acc1; o.z = acc2; o.w = acc3;
        *reinterpret_cast<float4*>(y + (size_t)node * NREL + rg * 4) = o;
        if (rg == 3) xr[node] = accR;
    }
}

// ---------------------------------------------------------------------------
// Kernel B: per-edge gather + segment-sum via atomics.
// ---------------------------------------------------------------------------
__global__ __launch_bounds__(256) void rgcn_edge_kernel(
    const int* __restrict__ src, const int* __restrict__ dst,
    const int* __restrict__ et, const float* __restrict__ y,
    float* __restrict__ agg, float* __restrict__ cnt, int e)
{
    int i = blockIdx.x * 256 + threadIdx.x;
    if (i < e) {
        int s = src[i];
        int d_ = dst[i];
        int r = et[i];
        float v = y[(size_t)s * NREL + r];
        atomicAdd(agg + d_, v);
        atomicAdd(cnt + d_, 1.0f);
    }
}

// ---------------------------------------------------------------------------
// Kernel C0: score[n] = tanh(agg/max(cnt,1) + xr + bias)
// (separate kernel so the scratch tail can be read before C1 clobbers it)
// ---------------------------------------------------------------------------
__global__ __launch_bounds__(256) void rgcn_score_kernel(
    const float* __restrict__ agg, const float* __restrict__ cnt,
    const float* __restrict__ xr, const float* __restrict__ bias,
    float* __restrict__ score, int n)
{
    int i = blockIdx.x * 256 + threadIdx.x;
    if (i < n) {
        float c = cnt[i];
        float m = agg[i] / fmaxf(c, 1.0f);
        score[i] = tanhf(m + xr[i] + bias[0]);
    }
}

// ---------------------------------------------------------------------------
// Kernel C1: x_out = x * score[:,None].  One wave handles one node's row
// (64 lanes x float4 = 256 floats), so the score load is a wave broadcast.
// ---------------------------------------------------------------------------
__global__ __launch_bounds__(256) void rgcn_scale_kernel(
    const float* __restrict__ x, const float* __restrict__ score,
    float* __restrict__ xo, int n)
{
    int gid = blockIdx.x * 256 + threadIdx.x;
    int node = gid >> 6;
    int f4 = gid & 63;
    if (node < n) {
        float s = score[node];
        float4 v = *reinterpret_cast<const float4*>(
                       x + (size_t)node * D + f4 * 4);
        v.x *= s; v.y *= s; v.z *= s; v.w *= s;
        *reinterpret_cast<float4*>(xo + (size_t)node * D + f4 * 4) = v;
    }
}

extern "C" void kernel_launch(void* const* d_in, const int* in_sizes, int n_in,
                              void* d_out, int out_size, void* d_ws, size_t ws_size,
                              hipStream_t stream)
{
    const float* x    = (const float*)d_in[0];
    const int*   ei   = (const int*)d_in[1];   // (2, E): src then dst
    const int*   et   = (const int*)d_in[2];
    const float* w    = (const float*)d_in[3]; // (R, D, 1) -> flat r*D+d
    const float* root = (const float*)d_in[4]; // (D, 1)    -> flat d
    const float* bias = (const float*)d_in[5];

    const int n = in_sizes[0] / D;   // 50000
    const int e = in_sizes[2];       // 800000

    float* out       = (float*)d_out;
    float* out_x     = out;                       // n*D floats
    float* out_score = out + (size_t)n * D;       // n floats

    // Scratch lives in the tail of the x_out region (clobbered only by the
    // final scale kernel, after everything has been consumed):
    //   y[n*16] | xr[n] | agg[n] | cnt[n]   (950,000 floats = 3.8 MB)
    const size_t total_x = (size_t)n * D;
    const size_t scratch = (size_t)n * NREL + 3 * (size_t)n;
    float* y   = out_x + (total_x - scratch);
    float* xr  = y + (size_t)n * NREL;
    float* agg = xr + n;
    float* cnt = agg + n;

    // zero the atomic accumulators (agg + cnt are adjacent)
    hipMemsetAsync(agg, 0, 2 * (size_t)n * sizeof(float), stream);

    dim3 blk(256);
    rgcn_y_kernel<<<dim3((n + 63) / 64), blk, 0, stream>>>(x, w, root, y, xr, n);
    rgcn_edge_kernel<<<dim3((e + 255) / 256), blk, 0, stream>>>(
        ei, ei + e, et, y, agg, cnt, e);
    rgcn_score_kernel<<<dim3((n + 255) / 256), blk, 0, stream>>>(
        agg, cnt, xr, bias, out_score, n);
    rgcn_scale_kernel<<<dim3((int)(((size_t)n * 64 + 255) / 256)), blk, 0, stream>>>(
        x, out_score, out_x, n);
}

// Round 4
// 90.431 us; speedup vs baseline: 1.5405x; 1.5405x over previous
//
#include <hip/hip_runtime.h>
#include <math.h>

#define D 256          // feature dim (fixed by reference)
#define NREL 16        // relation count
#define PACKK 4294967296.0   // 2^32: count encoded in high bits of the f64 accumulator

// ---------------------------------------------------------------------------
// Kernel A: y[n][r] = dot(x[n], W[r]) for r in [0,16), xr[n] = dot(x[n], root)
// Also zeroes acc[n] (rgroup 2 lanes), removing the separate memset dispatch.
// Block = 256 threads, handles 64 nodes. thread t: node = t&63, rgroup = t>>6.
// ---------------------------------------------------------------------------
__global__ __launch_bounds__(256) void rgcn_y_kernel(
    const float* __restrict__ x, const float* __restrict__ w,
    const float* __restrict__ root, float* __restrict__ y,
    float* __restrict__ xr, double* __restrict__ acc, int n)
{
    __shared__ float lds[64 * 65];
    const int t = threadIdx.x;
    const int nl = t & 63;
    const int rg = __builtin_amdgcn_readfirstlane(t >> 6);  // wave-uniform
    const int node = blockIdx.x * 64 + nl;
    const int base = blockIdx.x * 64;

    const float* w0 = w + (size_t)(rg * 4 + 0) * D;
    const float* w1 = w + (size_t)(rg * 4 + 1) * D;
    const float* w2 = w + (size_t)(rg * 4 + 2) * D;
    const float* w3 = w + (size_t)(rg * 4 + 3) * D;
    const float* w4 = (rg == 3) ? root : w0;  // root handled by rgroup 3

    float acc0 = 0.f, acc1 = 0.f, acc2 = 0.f, acc3 = 0.f, accR = 0.f;

    for (int c = 0; c < 4; ++c) {  // 4 chunks of 64 features
        #pragma unroll
        for (int j = 0; j < 4; ++j) {
            int flat = j * 256 + t;      // 0..1023
            int snl  = flat >> 4;        // staged node local 0..63
            int f4   = flat & 15;        // float4 index within 64-float chunk
            int gn   = base + snl;
            float4 v = make_float4(0.f, 0.f, 0.f, 0.f);
            if (gn < n)
                v = *reinterpret_cast<const float4*>(
                        x + (size_t)gn * D + c * 64 + f4 * 4);
            int a = snl * 65 + f4 * 4;
            lds[a + 0] = v.x; lds[a + 1] = v.y;
            lds[a + 2] = v.z; lds[a + 3] = v.w;
        }
        __syncthreads();

        const float* wc0 = w0 + c * 64;
        const float* wc1 = w1 + c * 64;
        const float* wc2 = w2 + c * 64;
        const float* wc3 = w3 + c * 64;
        const float* wc4 = w4 + c * 64;
        #pragma unroll
        for (int d = 0; d < 64; ++d) {
            float xv = lds[nl * 65 + d];
            acc0 = fmaf(xv, wc0[d], acc0);
            acc1 = fmaf(xv, wc1[d], acc1);
            acc2 = fmaf(xv, wc2[d], acc2);
            acc3 = fmaf(xv, wc3[d], acc3);
            accR = fmaf(xv, wc4[d], accR);
        }
        __syncthreads();
    }

    if (node < n) {
        float4 o; o.x = acc0; o.y = acc1; o.z = acc2; o.w = acc3;
        *reinterpret_cast<float4*>(y + (size_t)node * NREL + rg * 4) = o;
        if (rg == 3) xr[node] = accR;
        if (rg == 2) acc[node] = 0.0;   // zero accumulator (replaces memset)
    }
}

// ---------------------------------------------------------------------------
// Kernel B: per-edge gather + segment-sum via ONE packed f64 atomic per edge:
//   acc[dst] += msg + 2^32   (high bits carry the count, low bits the sum)
// Vectorized: 4 edges per thread via int4 loads.
// ---------------------------------------------------------------------------
__global__ __launch_bounds__(256) void rgcn_edge_kernel_v4(
    const int* __restrict__ src, const int* __restrict__ dst,
    const int* __restrict__ et, const float* __restrict__ y,
    double* __restrict__ acc, int e)
{
    int i = blockIdx.x * 256 + threadIdx.x;
    int i0 = i * 4;
    if (i0 + 3 < e) {
        int4 s = *reinterpret_cast<const int4*>(src + i0);
        int4 d = *reinterpret_cast<const int4*>(dst + i0);
        int4 r = *reinterpret_cast<const int4*>(et + i0);
        float m0 = y[(size_t)s.x * NREL + r.x];
        float m1 = y[(size_t)s.y * NREL + r.y];
        float m2 = y[(size_t)s.z * NREL + r.z];
        float m3 = y[(size_t)s.w * NREL + r.w];
        atomicAdd(acc + d.x, (double)m0 + PACKK);
        atomicAdd(acc + d.y, (double)m1 + PACKK);
        atomicAdd(acc + d.z, (double)m2 + PACKK);
        atomicAdd(acc + d.w, (double)m3 + PACKK);
    } else {
        for (int k = i0; k < e && k < i0 + 4; ++k) {
            int s = src[k], dd = dst[k], r = et[k];
            atomicAdd(acc + dd, (double)y[(size_t)s * NREL + r] + PACKK);
        }
    }
}

// scalar fallback (used only if edge-array halves aren't 16B-aligned, i.e. e%4!=0)
__global__ __launch_bounds__(256) void rgcn_edge_kernel_s(
    const int* __restrict__ src, const int* __restrict__ dst,
    const int* __restrict__ et, const float* __restrict__ y,
    double* __restrict__ acc, int e)
{
    int i = blockIdx.x * 256 + threadIdx.x;
    if (i < e) {
        int s = src[i], dd = dst[i], r = et[i];
        atomicAdd(acc + dd, (double)y[(size_t)s * NREL + r] + PACKK);
    }
}

// ---------------------------------------------------------------------------
// Kernel C0: decode acc -> (agg, cnt); score = tanh(agg/max(cnt,1) + xr + bias)
// ---------------------------------------------------------------------------
__global__ __launch_bounds__(256) void rgcn_score_kernel(
    const double* __restrict__ acc, const float* __restrict__ xr,
    const float* __restrict__ bias, float* __restrict__ score, int n)
{
    int i = blockIdx.x * 256 + threadIdx.x;
    if (i < n) {
        double v = acc[i];
        double c = floor(v * (1.0 / PACKK) + 0.5);   // exact count
        double a = v - c * PACKK;                    // exact low-bits extraction
        float m = (float)a / fmaxf((float)c, 1.0f);
        score[i] = tanhf(m + xr[i] + bias[0]);
    }
}

// ---------------------------------------------------------------------------
// Kernel C1: x_out = x * score[:,None].  One wave per node row.
// ---------------------------------------------------------------------------
__global__ __launch_bounds__(256) void rgcn_scale_kernel(
    const float* __restrict__ x, const float* __restrict__ score,
    float* __restrict__ xo, int n)
{
    int gid = blockIdx.x * 256 + threadIdx.x;
    int node = gid >> 6;
    int f4 = gid & 63;
    if (node < n) {
        float s = score[node];
        float4 v = *reinterpret_cast<const float4*>(
                       x + (size_t)node * D + f4 * 4);
        v.x *= s; v.y *= s; v.z *= s; v.w *= s;
        *reinterpret_cast<float4*>(xo + (size_t)node * D + f4 * 4) = v;
    }
}

extern "C" void kernel_launch(void* const* d_in, const int* in_sizes, int n_in,
                              void* d_out, int out_size, void* d_ws, size_t ws_size,
                              hipStream_t stream)
{
    const float* x    = (const float*)d_in[0];
    const int*   ei   = (const int*)d_in[1];   // (2, E): src then dst
    const int*   et   = (const int*)d_in[2];
    const float* w    = (const float*)d_in[3]; // (R, D, 1) -> flat r*D+d
    const float* root = (const float*)d_in[4]; // (D, 1)    -> flat d
    const float* bias = (const float*)d_in[5];

    const int n = in_sizes[0] / D;   // 50000
    const int e = in_sizes[2];       // 800000

    float* out       = (float*)d_out;
    float* out_x     = out;                       // n*D floats
    float* out_score = out + (size_t)n * D;       // n floats

    // Scratch: acc(double n) | xr(n) | y(16n)  = 19n floats = 3.8 MB.
    // Prefer d_ws; else tail of x_out region (fully consumed before the
    // scale kernel overwrites it).
    const size_t need_f = (size_t)n * 19;
    float* sb;
    if (ws_size >= need_f * sizeof(float))
        sb = (float*)d_ws;
    else {
        size_t ts = (((size_t)n * D - need_f) & ~(size_t)1);  // 8B-align
        sb = out_x + ts;
    }
    double* acc = (double*)sb;                 // 2n floats
    float*  xr  = sb + 2 * (size_t)n;          // n floats
    float*  y   = xr + n;                      // 16n floats

    dim3 blk(256);
    rgcn_y_kernel<<<dim3((n + 63) / 64), blk, 0, stream>>>(x, w, root, y, xr, acc, n);

    if ((e & 3) == 0) {
        int nthr = e / 4;
        rgcn_edge_kernel_v4<<<dim3((nthr + 255) / 256), blk, 0, stream>>>(
            ei, ei + e, et, y, acc, e);
    } else {
        rgcn_edge_kernel_s<<<dim3((e + 255) / 256), blk, 0, stream>>>(
            ei, ei + e, et, y, acc, e);
    }

    rgcn_score_kernel<<<dim3((n + 255) / 256), blk, 0, stream>>>(
        acc, xr, bias, out_score, n);
    rgcn_scale_kernel<<<dim3((int)(((size_t)n * 64 + 255) / 256)), blk, 0, stream>>>(
        x, out_score, out_x, n);
}

// Round 5
// 69.820 us; speedup vs baseline: 1.9953x; 1.2952x over previous
//
#include <hip/hip_runtime.h>
#include <math.h>

#define D 256          // feature dim (fixed by reference)
#define NREL 16        // relation count
#define CHUNK 6250     // nodes per dst-chunk (2 x f32 LDS arrays = 50 KB)
#define BPC 32         // blocks per chunk (edge-slice parallelism)

// ---------------------------------------------------------------------------
// Kernel A: y[n][r] = dot(x[n], W[r]) for r in [0,16), xr[n] = dot(x[n], root)
// Block = 256 threads, handles 64 nodes. thread t: node = t&63, rgroup = t>>6.
// ---------------------------------------------------------------------------
__global__ __launch_bounds__(256) void rgcn_y_kernel(
    const float* __restrict__ x, const float* __restrict__ w,
    const float* __restrict__ root, float* __restrict__ y,
    float* __restrict__ xr, int n)
{
    __shared__ float lds[64 * 65];
    const int t = threadIdx.x;
    const int nl = t & 63;
    const int rg = __builtin_amdgcn_readfirstlane(t >> 6);  // wave-uniform
    const int node = blockIdx.x * 64 + nl;
    const int base = blockIdx.x * 64;

    const float* w0 = w + (size_t)(rg * 4 + 0) * D;
    const float* w1 = w + (size_t)(rg * 4 + 1) * D;
    const float* w2 = w + (size_t)(rg * 4 + 2) * D;
    const float* w3 = w + (size_t)(rg * 4 + 3) * D;
    const float* w4 = (rg == 3) ? root : w0;  // root handled by rgroup 3

    float acc0 = 0.f, acc1 = 0.f, acc2 = 0.f, acc3 = 0.f, accR = 0.f;

    for (int c = 0; c < 4; ++c) {  // 4 chunks of 64 features
        #pragma unroll
        for (int j = 0; j < 4; ++j) {
            int flat = j * 256 + t;      // 0..1023
            int snl  = flat >> 4;        // staged node local 0..63
            int f4   = flat & 15;        // float4 index within 64-float chunk
            int gn   = base + snl;
            float4 v = make_float4(0.f, 0.f, 0.f, 0.f);
            if (gn < n)
                v = *reinterpret_cast<const float4*>(
                        x + (size_t)gn * D + c * 64 + f4 * 4);
            int a = snl * 65 + f4 * 4;
            lds[a + 0] = v.x; lds[a + 1] = v.y;
            lds[a + 2] = v.z; lds[a + 3] = v.w;
        }
        __syncthreads();

        const float* wc0 = w0 + c * 64;
        const float* wc1 = w1 + c * 64;
        const float* wc2 = w2 + c * 64;
        const float* wc3 = w3 + c * 64;
        const float* wc4 = w4 + c * 64;
        #pragma unroll
        for (int d = 0; d < 64; ++d) {
            float xv = lds[nl * 65 + d];
            acc0 = fmaf(xv, wc0[d], acc0);
            acc1 = fmaf(xv, wc1[d], acc1);
            acc2 = fmaf(xv, wc2[d], acc2);
            acc3 = fmaf(xv, wc3[d], acc3);
            accR = fmaf(xv, wc4[d], accR);
        }
        __syncthreads();
    }

    if (node < n) {
        float4 o; o.x = acc0; o.y = acc1; o.z = acc2; o.w = acc3;
        *reinterpret_cast<float4*>(y + (size_t)node * NREL + rg * 4) = o;
        if (rg == 3) xr[node] = accR;
    }
}

// ---------------------------------------------------------------------------
// Kernel B: chunked edge scan, LDS accumulation, ZERO global atomics.
// Grid = C chunks x BPC blocks. Block (c,b): scan edge slice b; edges whose
// dst falls in chunk c accumulate (msg, 1) into LDS via ds_add_f32; flush
// the chunk's (sum,cnt) pairs as coalesced float2 partials.
// ---------------------------------------------------------------------------
__global__ __launch_bounds__(1024) void rgcn_edge_scan_kernel(
    const int* __restrict__ src, const int* __restrict__ dst,
    const int* __restrict__ et, const float* __restrict__ y,
    float2* __restrict__ partial, int e, int n, int sl)
{
    __shared__ float lsum[CHUNK];
    __shared__ float lcnt[CHUNK];
    const int t = threadIdx.x;
    const int c = blockIdx.x / BPC;
    const int b = blockIdx.x % BPC;
    const int base = c * CHUNK;

    for (int j = t; j < CHUNK; j += 1024) { lsum[j] = 0.f; lcnt[j] = 0.f; }
    __syncthreads();

    const int slice0 = b * sl;
    const int rem = e - slice0;
    if (rem > 0) {
        const int gmax = (min(sl, rem) + 3) >> 2;   // int4 groups in slice
        for (int g = t; g < gmax; g += 1024) {
            int idx = slice0 + g * 4;
            if (idx + 3 < e) {
                int4 d4 = *reinterpret_cast<const int4*>(dst + idx);
                #pragma unroll
                for (int k = 0; k < 4; ++k) {
                    int dd = (k == 0) ? d4.x : (k == 1) ? d4.y
                           : (k == 2) ? d4.z : d4.w;
                    int loc = dd - base;
                    if ((unsigned)loc < (unsigned)CHUNK) {
                        int s = src[idx + k];
                        int r = et[idx + k];
                        float m = y[(size_t)s * NREL + r];
                        atomicAdd(&lsum[loc], m);
                        atomicAdd(&lcnt[loc], 1.0f);
                    }
                }
            } else {
                for (int k = idx; k < e; ++k) {
                    int loc = dst[k] - base;
                    if ((unsigned)loc < (unsigned)CHUNK) {
                        float m = y[(size_t)src[k] * NREL + et[k]];
                        atomicAdd(&lsum[loc], m);
                        atomicAdd(&lcnt[loc], 1.0f);
                    }
                }
            }
        }
    }
    __syncthreads();

    // flush: partial[(c*BPC + b)*CHUNK + j] = (sum, cnt)
    float2* p = partial + ((size_t)(c * BPC + b)) * CHUNK;
    for (int j = t; j < CHUNK; j += 1024)
        p[j] = make_float2(lsum[j], lcnt[j]);
}

// ---------------------------------------------------------------------------
// Kernel C0: reduce partials over BPC blocks + score = tanh(mean + xr + bias)
// ---------------------------------------------------------------------------
__global__ __launch_bounds__(256) void rgcn_reduce_score_kernel(
    const float2* __restrict__ partial, const float* __restrict__ xr,
    const float* __restrict__ bias, float* __restrict__ score, int n)
{
    int i = blockIdx.x * 256 + threadIdx.x;
    if (i < n) {
        int c = i / CHUNK;
        int j = i - c * CHUNK;
        const float2* p = partial + (size_t)c * BPC * CHUNK + j;
        float s = 0.f, cN = 0.f;
        #pragma unroll 8
        for (int b = 0; b < BPC; ++b) {
            float2 v = p[(size_t)b * CHUNK];
            s += v.x; cN += v.y;
        }
        float m = s / fmaxf(cN, 1.0f);
        score[i] = tanhf(m + xr[i] + bias[0]);
    }
}

// ---------------------------------------------------------------------------
// Kernel C1: x_out = x * score[:,None].  One wave per node row.
// ---------------------------------------------------------------------------
__global__ __launch_bounds__(256) void rgcn_scale_kernel(
    const float* __restrict__ x, const float* __restrict__ score,
    float* __restrict__ xo, int n)
{
    int gid = blockIdx.x * 256 + threadIdx.x;
    int node = gid >> 6;
    int f4 = gid & 63;
    if (node < n) {
        float s = score[node];
        float4 v = *reinterpret_cast<const float4*>(
                       x + (size_t)node * D + f4 * 4);
        v.x *= s; v.y *= s; v.z *= s; v.w *= s;
        *reinterpret_cast<float4*>(xo + (size_t)node * D + f4 * 4) = v;
    }
}

extern "C" void kernel_launch(void* const* d_in, const int* in_sizes, int n_in,
                              void* d_out, int out_size, void* d_ws, size_t ws_size,
                              hipStream_t stream)
{
    const float* x    = (const float*)d_in[0];
    const int*   ei   = (const int*)d_in[1];   // (2, E): src then dst
    const int*   et   = (const int*)d_in[2];
    const float* w    = (const float*)d_in[3]; // (R, D, 1) -> flat r*D+d
    const float* root = (const float*)d_in[4]; // (D, 1)    -> flat d
    const float* bias = (const float*)d_in[5];

    const int n = in_sizes[0] / D;   // 50000
    const int e = in_sizes[2];       // 800000

    float* out       = (float*)d_out;
    float* out_x     = out;                       // n*D floats
    float* out_score = out + (size_t)n * D;       // n floats

    const int C = (n + CHUNK - 1) / CHUNK;        // 8 for n=50000
    // slice length per block, multiple of 4 for int4 loads
    const int sl = ((((e + BPC - 1) / BPC) + 3) & ~3);

    // Scratch: partials (C*BPC*CHUNK float2) | y (16n) | xr (n)
    const size_t part_f = (size_t)C * BPC * CHUNK * 2;   // floats
    const size_t need_f = part_f + (size_t)n * (NREL + 1);
    float* sb;
    if (ws_size >= need_f * sizeof(float))
        sb = (float*)d_ws;
    else {
        // tail of the x_out region: fully consumed before C1 overwrites it
        size_t ts = (((size_t)n * D - need_f) & ~(size_t)1);  // 8B-align
        sb = out_x + ts;
    }
    float2* partial = (float2*)sb;
    float*  y  = sb + part_f;
    float*  xr = y + (size_t)n * NREL;

    dim3 blk(256);
    rgcn_y_kernel<<<dim3((n + 63) / 64), blk, 0, stream>>>(x, w, root, y, xr, n);

    rgcn_edge_scan_kernel<<<dim3(C * BPC), dim3(1024), 0, stream>>>(
        ei, ei + e, et, y, partial, e, n, sl);

    rgcn_reduce_score_kernel<<<dim3((n + 255) / 256), blk, 0, stream>>>(
        partial, xr, bias, out_score, n);

    rgcn_scale_kernel<<<dim3((int)(((size_t)n * 64 + 255) / 256)), blk, 0, stream>>>(
        x, out_score, out_x, n);
}

// Round 6
// 63.397 us; speedup vs baseline: 2.1975x; 1.1013x over previous
//
#include <hip/hip_runtime.h>
#include <math.h>

#define D 256          // feature dim (fixed by reference)
#define NREL 16        // relation count
#define CHUNK 6250     // nodes per dst-chunk (2 x f32 LDS arrays = 50 KB)
#define BPC 32         // blocks per chunk (edge-slice parallelism)

// ---------------------------------------------------------------------------
// Kernel A: y[n][r] = dot(x[n], W[r]) for r in [0,16), xr[n] = dot(x[n], root)
// Block = 256 threads, handles 64 nodes. thread t: node = t&63, rgroup = t>>6.
// ---------------------------------------------------------------------------
__global__ __launch_bounds__(256) void rgcn_y_kernel(
    const float* __restrict__ x, const float* __restrict__ w,
    const float* __restrict__ root, float* __restrict__ y,
    float* __restrict__ xr, int n)
{
    __shared__ float lds[64 * 65];
    const int t = threadIdx.x;
    const int nl = t & 63;
    const int rg = __builtin_amdgcn_readfirstlane(t >> 6);  // wave-uniform
    const int node = blockIdx.x * 64 + nl;
    const int base = blockIdx.x * 64;

    const float* w0 = w + (size_t)(rg * 4 + 0) * D;
    const float* w1 = w + (size_t)(rg * 4 + 1) * D;
    const float* w2 = w + (size_t)(rg * 4 + 2) * D;
    const float* w3 = w + (size_t)(rg * 4 + 3) * D;
    const float* w4 = (rg == 3) ? root : w0;  // root handled by rgroup 3

    float acc0 = 0.f, acc1 = 0.f, acc2 = 0.f, acc3 = 0.f, accR = 0.f;

    for (int c = 0; c < 4; ++c) {  // 4 chunks of 64 features
        #pragma unroll
        for (int j = 0; j < 4; ++j) {
            int flat = j * 256 + t;      // 0..1023
            int snl  = flat >> 4;        // staged node local 0..63
            int f4   = flat & 15;        // float4 index within 64-float chunk
            int gn   = base + snl;
            float4 v = make_float4(0.f, 0.f, 0.f, 0.f);
            if (gn < n)
                v = *reinterpret_cast<const float4*>(
                        x + (size_t)gn * D + c * 64 + f4 * 4);
            int a = snl * 65 + f4 * 4;
            lds[a + 0] = v.x; lds[a + 1] = v.y;
            lds[a + 2] = v.z; lds[a + 3] = v.w;
        }
        __syncthreads();

        const float* wc0 = w0 + c * 64;
        const float* wc1 = w1 + c * 64;
        const float* wc2 = w2 + c * 64;
        const float* wc3 = w3 + c * 64;
        const float* wc4 = w4 + c * 64;
        #pragma unroll
        for (int d = 0; d < 64; ++d) {
            float xv = lds[nl * 65 + d];
            acc0 = fmaf(xv, wc0[d], acc0);
            acc1 = fmaf(xv, wc1[d], acc1);
            acc2 = fmaf(xv, wc2[d], acc2);
            acc3 = fmaf(xv, wc3[d], acc3);
            accR = fmaf(xv, wc4[d], accR);
        }
        __syncthreads();
    }

    if (node < n) {
        float4 o; o.x = acc0; o.y = acc1; o.z = acc2; o.w = acc3;
        *reinterpret_cast<float4*>(y + (size_t)node * NREL + rg * 4) = o;
        if (rg == 3) xr[node] = accR;
    }
}

// ---------------------------------------------------------------------------
// Kernel B: chunked edge scan, LDS accumulation, zero global atomics.
// v2: unconditional int4 loads of dst AND src AND et (3 independent vector
// loads per 4-edge group -> deep MLP instead of dependent scalar chains).
// ---------------------------------------------------------------------------
__global__ __launch_bounds__(1024) void rgcn_edge_scan_kernel(
    const int* __restrict__ src, const int* __restrict__ dst,
    const int* __restrict__ et, const float* __restrict__ y,
    float2* __restrict__ partial, int e, int sl)
{
    __shared__ float lsum[CHUNK];
    __shared__ float lcnt[CHUNK];
    const int t = threadIdx.x;
    const int c = blockIdx.x / BPC;
    const int b = blockIdx.x % BPC;
    const int base = c * CHUNK;

    for (int j = t; j < CHUNK; j += 1024) { lsum[j] = 0.f; lcnt[j] = 0.f; }
    __syncthreads();

    const int slice0 = b * sl;
    const int rem = e - slice0;
    if (rem > 0) {
        const int gmax = (min(sl, rem) + 3) >> 2;   // int4 groups in slice
        for (int g = t; g < gmax; g += 1024) {
            int idx = slice0 + g * 4;
            if (idx + 3 < e) {
                int4 d4 = *reinterpret_cast<const int4*>(dst + idx);
                int4 s4 = *reinterpret_cast<const int4*>(src + idx);
                int4 r4 = *reinterpret_cast<const int4*>(et + idx);
                int loc0 = d4.x - base, loc1 = d4.y - base;
                int loc2 = d4.z - base, loc3 = d4.w - base;
                if ((unsigned)loc0 < (unsigned)CHUNK) {
                    atomicAdd(&lsum[loc0], y[(size_t)s4.x * NREL + r4.x]);
                    atomicAdd(&lcnt[loc0], 1.0f);
                }
                if ((unsigned)loc1 < (unsigned)CHUNK) {
                    atomicAdd(&lsum[loc1], y[(size_t)s4.y * NREL + r4.y]);
                    atomicAdd(&lcnt[loc1], 1.0f);
                }
                if ((unsigned)loc2 < (unsigned)CHUNK) {
                    atomicAdd(&lsum[loc2], y[(size_t)s4.z * NREL + r4.z]);
                    atomicAdd(&lcnt[loc2], 1.0f);
                }
                if ((unsigned)loc3 < (unsigned)CHUNK) {
                    atomicAdd(&lsum[loc3], y[(size_t)s4.w * NREL + r4.w]);
                    atomicAdd(&lcnt[loc3], 1.0f);
                }
            } else {
                for (int k = idx; k < e; ++k) {
                    int loc = dst[k] - base;
                    if ((unsigned)loc < (unsigned)CHUNK) {
                        atomicAdd(&lsum[loc], y[(size_t)src[k] * NREL + et[k]]);
                        atomicAdd(&lcnt[loc], 1.0f);
                    }
                }
            }
        }
    }
    __syncthreads();

    float2* p = partial + ((size_t)(c * BPC + b)) * CHUNK;
    for (int j = t; j < CHUNK; j += 1024)
        p[j] = make_float2(lsum[j], lcnt[j]);
}

// ---------------------------------------------------------------------------
// Kernel C (fused): per 64-node block:
//   phase 1 (wave 0): reduce 32 partials/node, score = tanh(mean+xr+bias)
//                     -> LDS + out_score
//   phase 2 (all):    x_out = x * score, per-wave 1KB coalesced float4
// ---------------------------------------------------------------------------
__global__ __launch_bounds__(256) void rgcn_finish_kernel(
    const float2* __restrict__ partial, const float* __restrict__ xr,
    const float* __restrict__ bias, const float* __restrict__ x,
    float* __restrict__ out_x, float* __restrict__ out_score, int n)
{
    __shared__ float sc[64];
    const int t = threadIdx.x;
    const int base = blockIdx.x * 64;

    if (t < 64) {
        int node = base + t;
        if (node < n) {
            int c = node / CHUNK;
            int j = node - c * CHUNK;
            const float2* p = partial + (size_t)c * BPC * CHUNK + j;
            float s = 0.f, cN = 0.f;
            #pragma unroll 8
            for (int b = 0; b < BPC; ++b) {
                float2 v = p[(size_t)b * CHUNK];
                s += v.x; cN += v.y;
            }
            float m = s / fmaxf(cN, 1.0f);
            float v = tanhf(m + xr[node] + bias[0]);
            sc[t] = v;
            out_score[node] = v;
        }
    }
    __syncthreads();

    #pragma unroll 4
    for (int k = 0; k < 16; ++k) {
        int flat = k * 256 + t;          // 0..4095
        int nl = flat >> 6;              // node local 0..63
        int f4 = flat & 63;              // float4 index in row
        int node = base + nl;
        if (node < n) {
            float s = sc[nl];
            float4 v = *reinterpret_cast<const float4*>(
                           x + (size_t)node * D + f4 * 4);
            v.x *= s; v.y *= s; v.z *= s; v.w *= s;
            *reinterpret_cast<float4*>(out_x + (size_t)node * D + f4 * 4) = v;
        }
    }
}

// --------------------- fallback path (scratch in out tail) -----------------
__global__ __launch_bounds__(256) void rgcn_reduce_score_kernel(
    const float2* __restrict__ partial, const float* __restrict__ xr,
    const float* __restrict__ bias, float* __restrict__ score, int n)
{
    int i = blockIdx.x * 256 + threadIdx.x;
    if (i < n) {
        int c = i / CHUNK;
        int j = i - c * CHUNK;
        const float2* p = partial + (size_t)c * BPC * CHUNK + j;
        float s = 0.f, cN = 0.f;
        #pragma unroll 8
        for (int b = 0; b < BPC; ++b) {
            float2 v = p[(size_t)b * CHUNK];
            s += v.x; cN += v.y;
        }
        float m = s / fmaxf(cN, 1.0f);
        score[i] = tanhf(m + xr[i] + bias[0]);
    }
}

__global__ __launch_bounds__(256) void rgcn_scale_kernel(
    const float* __restrict__ x, const float* __restrict__ score,
    float* __restrict__ xo, int n)
{
    int gid = blockIdx.x * 256 + threadIdx.x;
    int node = gid >> 6;
    int f4 = gid & 63;
    if (node < n) {
        float s = score[node];
        float4 v = *reinterpret_cast<const float4*>(
                       x + (size_t)node * D + f4 * 4);
        v.x *= s; v.y *= s; v.z *= s; v.w *= s;
        *reinterpret_cast<float4*>(xo + (size_t)node * D + f4 * 4) = v;
    }
}

extern "C" void kernel_launch(void* const* d_in, const int* in_sizes, int n_in,
                              void* d_out, int out_size, void* d_ws, size_t ws_size,
                              hipStream_t stream)
{
    const float* x    = (const float*)d_in[0];
    const int*   ei   = (const int*)d_in[1];   // (2, E): src then dst
    const int*   et   = (const int*)d_in[2];
    const float* w    = (const float*)d_in[3]; // (R, D, 1) -> flat r*D+d
    const float* root = (const float*)d_in[4]; // (D, 1)    -> flat d
    const float* bias = (const float*)d_in[5];

    const int n = in_sizes[0] / D;   // 50000
    const int e = in_sizes[2];       // 800000

    float* out       = (float*)d_out;
    float* out_x     = out;                       // n*D floats
    float* out_score = out + (size_t)n * D;       // n floats

    const int C = (n + CHUNK - 1) / CHUNK;        // 8 for n=50000
    const int sl = ((((e + BPC - 1) / BPC) + 3) & ~3);  // slice len, mult of 4

    // Scratch: partials (C*BPC*CHUNK float2) | y (16n) | xr (n)
    const size_t part_f = (size_t)C * BPC * CHUNK * 2;   // floats
    const size_t need_f = part_f + (size_t)n * (NREL + 1);
    const bool use_ws = (ws_size >= need_f * sizeof(float));

    float* sb;
    if (use_ws)
        sb = (float*)d_ws;
    else {
        size_t ts = (((size_t)n * D - need_f) & ~(size_t)1);  // 8B-align
        sb = out_x + ts;
    }
    float2* partial = (float2*)sb;
    float*  y  = sb + part_f;
    float*  xr = y + (size_t)n * NREL;

    dim3 blk(256);
    rgcn_y_kernel<<<dim3((n + 63) / 64), blk, 0, stream>>>(x, w, root, y, xr, n);

    rgcn_edge_scan_kernel<<<dim3(C * BPC), dim3(1024), 0, stream>>>(
        ei, ei + e, et, y, partial, e, sl);

    if (use_ws) {
        // fused reduce+score+scale (scratch is in d_ws -> no write/read race)
        rgcn_finish_kernel<<<dim3((n + 63) / 64), blk, 0, stream>>>(
            partial, xr, bias, x, out_x, out_score, n);
    } else {
        rgcn_reduce_score_kernel<<<dim3((n + 255) / 256), blk, 0, stream>>>(
            partial, xr, bias, out_score, n);
        rgcn_scale_kernel<<<dim3((int)(((size_t)n * 64 + 255) / 256)), blk, 0, stream>>>(
            x, out_score, out_x, n);
    }
}